// Round 7
// baseline (311.839 us; speedup 1.0000x reference)
//
#include <hip/hip_runtime.h>
#include <hip/hip_fp16.h>

// GCN VGAE encoder:
//   h  = relu((A @ x) @ W1 + b1)          [associativity: A(xW) == (Ax)W]
//   mu = (A @ h) @ Wmu + bmu ; lv = (A @ h) @ Wlv + blv
// A = D^-1/2 (Adj + I) D^-1/2, deg on dst side. dinv folded into tables:
//   xs[s]=dinv_s*x[s]; hs[i]=dinv_i*relu(...); y_i = dinv_i*(sum_e xs[src]+xs[i])
//
// R7 (vs R6): aggs were latency-bound at 30% occupancy -- 34KB LDS/block
// capped 4 blocks/CU. Extra xor-16 fold shrinks the MFMA A-tile K' 256->128:
// LDS/block 34->17.7KB, launch_bounds(256,6) -> ~24 waves/CU. MFMA k-steps
// halve (epilogue was over-provisioned at MfmaUtil 1.5%). Duplicate LDS
// stores predicated to g<2.

#define BKT_SHIFT 9
#define BKT_NODES 512
#define CHUNK 8192

typedef __attribute__((ext_vector_type(8))) _Float16 half8;
typedef __attribute__((ext_vector_type(4))) float float4v;

__device__ __forceinline__ int imin(int a, int b) { return a < b ? a : b; }

// ---------------- scan building blocks (for the (bucket,block) table) ------

__global__ __launch_bounds__(1024) void block_sums(const int* __restrict__ in,
                                                   int* __restrict__ bsum, int n) {
  __shared__ int s[1024];
  int t = threadIdx.x;
  int i = blockIdx.x * 1024 + t;
  s[t] = (i < n) ? in[i] : 0;
  __syncthreads();
  for (int off = 512; off > 0; off >>= 1) {
    if (t < off) s[t] += s[t + off];
    __syncthreads();
  }
  if (t == 0) bsum[blockIdx.x] = s[0];
}

__global__ __launch_bounds__(1024) void scan_bsums(int* __restrict__ bsum, int nb) {
  __shared__ int s[1024];
  int t = threadIdx.x;
  int v = (t < nb) ? bsum[t] : 0;
  s[t] = v;
  __syncthreads();
  for (int off = 1; off < 1024; off <<= 1) {
    int u = (t >= off) ? s[t - off] : 0;
    __syncthreads();
    s[t] += u;
    __syncthreads();
  }
  if (t < nb) bsum[t] = s[t] - v;  // exclusive
}

__global__ __launch_bounds__(1024) void scan_apply(int* __restrict__ data,
                                                   const int* __restrict__ bofs, int n) {
  __shared__ int s[1024];
  int t = threadIdx.x;
  int i = blockIdx.x * 1024 + t;
  int c = (i < n) ? data[i] : 0;
  s[t] = c;
  __syncthreads();
  for (int off = 1; off < 1024; off <<= 1) {
    int u = (t >= off) ? s[t - off] : 0;
    __syncthreads();
    s[t] += u;
    __syncthreads();
  }
  if (i < n) data[i] = bofs[blockIdx.x] + s[t] - c;
}

// ---------------- two-level CSR build (no global atomics) ------------------

// A0: per-chunk bucket histogram -> cnt[bucket*nblk + block] (bucket-major).
__global__ __launch_bounds__(256) void bucket_count(const int* __restrict__ dst,
                                                    int* __restrict__ cnt,
                                                    int E, int nbk, int nblk) {
  __shared__ int hist[256];
  int t = threadIdx.x;
  hist[t] = 0;
  __syncthreads();
  int base = blockIdx.x * CHUNK;
  int end = imin(base + CHUNK, E);
  for (int e = base + t; e < end; e += 256) atomicAdd(&hist[dst[e] >> BKT_SHIFT], 1);
  __syncthreads();
  if (t < nbk) cnt[t * nblk + blockIdx.x] = hist[t];
}

// A1: re-read edges; LDS cursors from scanned bases; contiguous runs to tmp.
__global__ __launch_bounds__(256) void bucket_scatter(const int* __restrict__ src,
                                                      const int* __restrict__ dst,
                                                      const int* __restrict__ ofs,
                                                      int2* __restrict__ tmp,
                                                      int E, int nbk, int nblk) {
  __shared__ int cur[256];
  int t = threadIdx.x;
  if (t < nbk) cur[t] = ofs[t * nblk + blockIdx.x];
  __syncthreads();
  int base = blockIdx.x * CHUNK;
  int end = imin(base + CHUNK, E);
  for (int e = base + t; e < end; e += 256) {
    int d = dst[e];
    int pos = atomicAdd(&cur[d >> BKT_SHIFT], 1);
    tmp[pos] = make_int2(src[e], d);
  }
}

// B: one block per bucket. LDS node histogram -> LDS scan -> row_ptr/dinv
// (coalesced) -> LDS-cursor fill of pairs inside the bucket's window.
__global__ __launch_bounds__(512) void bucket_build(const int2* __restrict__ tmp,
                                                    const int* __restrict__ ofs,
                                                    int* __restrict__ row_ptr,
                                                    float* __restrict__ dinv,
                                                    int* __restrict__ pairs,
                                                    int n, int nbk, int nblk, int E) {
  __shared__ int hist[BKT_NODES];
  __shared__ int scn[BKT_NODES];
  const int b = blockIdx.x;
  const int t = threadIdx.x;
  const int node0 = b << BKT_SHIFT;
  hist[t] = 0;
  __syncthreads();
  const int s = ofs[b * nblk];
  const int e = (b + 1 < nbk) ? ofs[(b + 1) * nblk] : E;
  for (int k = s + t; k < e; k += 512) atomicAdd(&hist[tmp[k].y - node0], 1);
  __syncthreads();
  int v = hist[t];
  scn[t] = v;
  __syncthreads();
  for (int off = 1; off < 512; off <<= 1) {
    int u = (t >= off) ? scn[t - off] : 0;
    __syncthreads();
    scn[t] += u;
    __syncthreads();
  }
  int excl = s + scn[t] - v;  // exclusive prefix = CSR start of node0+t
  int node = node0 + t;
  if (node < n) {
    row_ptr[node] = excl;
    dinv[node] = rsqrtf(1.0f + (float)v);  // deg includes self-loop
  }
  if (b == nbk - 1 && t == 0) row_ptr[n] = E;
  hist[t] = excl;  // reuse as cursor
  __syncthreads();
  for (int k = s + t; k < e; k += 512) {
    int2 p = tmp[k];
    int pos = atomicAdd(&hist[p.y - node0], 1);
    pairs[pos] = p.x;
  }
}

// ---------------- table prep ----------------

// xs[i] = dinv[i] * x[i] in fp16; zeros sentinel row `nrow` of xs and hs.
__global__ __launch_bounds__(256) void cast_scale(const float* __restrict__ x,
                                                  const float* __restrict__ dinv,
                                                  __half* __restrict__ xs,
                                                  __half* __restrict__ hs,
                                                  int n4, int nrow) {
  int i = blockIdx.x * blockDim.x + threadIdx.x;
  if (i < n4) {
    float4 v = ((const float4*)x)[i];
    float d = dinv[i >> 4];
    __half2* o = (__half2*)(xs + (size_t)i * 4);
    o[0] = __floats2half2_rn(d * v.x, d * v.y);
    o[1] = __floats2half2_rn(d * v.z, d * v.w);
  } else if (i < n4 + 32) {
    int j = i - n4;
    if (j < 16)
      ((float2*)(xs + (size_t)nrow * 64))[j] = make_float2(0.f, 0.f);
    else
      ((float2*)(hs + (size_t)nrow * 64))[j - 16] = make_float2(0.f, 0.f);
  }
}

// ---------------- aggregation + fused dense via MFMA ----------------
// Wave handles 16 rows. Per row: 8-edges-in-flight gather (lane=8g+q, 16B of
// 8 halves per lane), xor-32 + xor-16 folds (groups 8->2), di-scale, fp16 ->
// ylds[row][(g&1)*64 + 8q+c] (A-tile, K'=128; last 2-slot reduction rides
// the MFMA K-dim, B = W replicated over the 2 slots). 4 k-steps x 4 n-tiles
// of mfma_f32_16x16x32_f16, bias in C-init.
// A layout: A[m=lane&15][k=(lane>>4)*8+j]; C/D: col=lane&15, row=quad*4+reg.

#define YSTRIDE 136  // 128 + 8 halves pad

__global__ __launch_bounds__(256, 6) void agg_layer1(const __half* __restrict__ xs,
                                                     const int* __restrict__ pairs,
                                                     const int* __restrict__ row_ptr,
                                                     const float* __restrict__ W1,
                                                     const float* __restrict__ b1,
                                                     __half* __restrict__ hs, int n) {
  __shared__ _Float16 ylds_all[4][16 * YSTRIDE];
  __shared__ float dilds_all[4][16];
  const int wv = threadIdx.x >> 6;
  _Float16* ylds = ylds_all[wv];
  float* dilds = dilds_all[wv];
  const int lane = threadIdx.x & 63;
  const int g = lane >> 3, q = lane & 7;
  const int quad = lane >> 4, col = lane & 15;

  // B-fragments: bfrag[s][t][jj] = W1[(s*32 + quad*8 + jj) & 63... ][t*16+col]
  // k = s2*32 + quad*8 + jj, feature = k & 63 -> sW = s2 & 1.
  half8 bfrag[2][4];
#pragma unroll
  for (int s = 0; s < 2; ++s)
#pragma unroll
    for (int t = 0; t < 4; ++t)
#pragma unroll
      for (int jj = 0; jj < 8; ++jj)
        bfrag[s][t][jj] = (_Float16)W1[(s * 32 + quad * 8 + jj) * 64 + t * 16 + col];
  float bias[4];
#pragma unroll
  for (int t = 0; t < 4; ++t) bias[t] = b1[t * 16 + col];

  const int ntiles = (n + 15) >> 4;
  for (int tile = blockIdx.x * 4 + wv; tile < ntiles; tile += gridDim.x * 4) {
    const int row0 = tile << 4;
    for (int r = 0; r < 16; ++r) {
      const int i = row0 + r;
      int start = 0, end = 0;
      if (i < n) { start = row_ptr[i]; end = row_ptr[i + 1]; }
      float a0 = 0, a1 = 0, a2 = 0, a3 = 0, a4 = 0, a5 = 0, a6 = 0, a7 = 0;
      int idx = (start + g < end) ? pairs[start + g] : n;
      for (int base = start; base < end; base += 8) {
        int idxn = (base + 8 + g < end) ? pairs[base + 8 + g] : n;  // prefetch
        const float4 rr = *(const float4*)(xs + (size_t)idx * 64 + q * 8);
        const __half2* hp = (const __half2*)&rr;
        float2 f0 = __half22float2(hp[0]), f1 = __half22float2(hp[1]);
        float2 f2 = __half22float2(hp[2]), f3 = __half22float2(hp[3]);
        a0 += f0.x; a1 += f0.y; a2 += f1.x; a3 += f1.y;
        a4 += f2.x; a5 += f2.y; a6 += f3.x; a7 += f3.y;
        idx = idxn;
      }
      // self term (g==0 only; sentinel row for i>=n)
      const int iself = (i < n) ? i : n;
      const float4 sr = *(const float4*)(xs + (size_t)iself * 64 + q * 8);
      if (g == 0 && i < n) {
        const __half2* hp = (const __half2*)&sr;
        float2 f0 = __half22float2(hp[0]), f1 = __half22float2(hp[1]);
        float2 f2 = __half22float2(hp[2]), f3 = __half22float2(hp[3]);
        a0 += f0.x; a1 += f0.y; a2 += f1.x; a3 += f1.y;
        a4 += f2.x; a5 += f2.y; a6 += f3.x; a7 += f3.y;
      }
      // fold groups 8 -> 2 (xor-32 then xor-16)
      a0 += __shfl_xor(a0, 32); a1 += __shfl_xor(a1, 32);
      a2 += __shfl_xor(a2, 32); a3 += __shfl_xor(a3, 32);
      a4 += __shfl_xor(a4, 32); a5 += __shfl_xor(a5, 32);
      a6 += __shfl_xor(a6, 32); a7 += __shfl_xor(a7, 32);
      a0 += __shfl_xor(a0, 16); a1 += __shfl_xor(a1, 16);
      a2 += __shfl_xor(a2, 16); a3 += __shfl_xor(a3, 16);
      a4 += __shfl_xor(a4, 16); a5 += __shfl_xor(a5, 16);
      a6 += __shfl_xor(a6, 16); a7 += __shfl_xor(a7, 16);
      const float di = rsqrtf((float)(1 + end - start));
      if (g < 2) {
        half8 yv;
        yv[0] = (_Float16)(di * a0); yv[1] = (_Float16)(di * a1);
        yv[2] = (_Float16)(di * a2); yv[3] = (_Float16)(di * a3);
        yv[4] = (_Float16)(di * a4); yv[5] = (_Float16)(di * a5);
        yv[6] = (_Float16)(di * a6); yv[7] = (_Float16)(di * a7);
        *(half8*)(ylds + r * YSTRIDE + g * 64 + q * 8) = yv;
      }
      if (lane == 0) dilds[r] = di;
    }
    // MFMA: D = A(16x128) * B'(128x64) + bias
    float4v acc[4];
#pragma unroll
    for (int t = 0; t < 4; ++t) acc[t] = (float4v){bias[t], bias[t], bias[t], bias[t]};
#pragma unroll
    for (int s2 = 0; s2 < 4; ++s2) {
      half8 af = *(half8*)(ylds + col * YSTRIDE + s2 * 32 + quad * 8);
      const int sW = s2 & 1;
#pragma unroll
      for (int t = 0; t < 4; ++t)
        acc[t] = __builtin_amdgcn_mfma_f32_16x16x32_f16(af, bfrag[sW][t], acc[t], 0, 0, 0);
    }
    const float4 dis = *(const float4*)(dilds + quad * 4);
    const float dd[4] = {dis.x, dis.y, dis.z, dis.w};
#pragma unroll
    for (int t = 0; t < 4; ++t)
#pragma unroll
      for (int reg = 0; reg < 4; ++reg) {
        const int row = row0 + quad * 4 + reg;
        if (row < n)
          hs[(size_t)row * 64 + t * 16 + col] =
              __float2half(dd[reg] * fmaxf(acc[t][reg], 0.f));
      }
  }
}

// Layer 2: same structure; B' = [Wmu | Wlv] (64 cols), fp32 outputs.
__global__ __launch_bounds__(256, 6) void agg_layer2(const __half* __restrict__ hsin,
                                                     const int* __restrict__ pairs,
                                                     const int* __restrict__ row_ptr,
                                                     const float* __restrict__ Wmu,
                                                     const float* __restrict__ bmu,
                                                     const float* __restrict__ Wlv,
                                                     const float* __restrict__ blv,
                                                     float* __restrict__ out_mu,
                                                     float* __restrict__ out_lv, int n) {
  __shared__ _Float16 ylds_all[4][16 * YSTRIDE];
  const int wv = threadIdx.x >> 6;
  _Float16* ylds = ylds_all[wv];
  const int lane = threadIdx.x & 63;
  const int g = lane >> 3, q = lane & 7;
  const int quad = lane >> 4, col = lane & 15;

  half8 bfrag[2][4];
#pragma unroll
  for (int s = 0; s < 2; ++s)
#pragma unroll
    for (int t = 0; t < 4; ++t) {
      const int j = t * 16 + col;
      const float* W = (j < 32) ? Wmu : Wlv;
      const int jc = j & 31;
#pragma unroll
      for (int jj = 0; jj < 8; ++jj)
        bfrag[s][t][jj] = (_Float16)W[(s * 32 + quad * 8 + jj) * 32 + jc];
    }
  float bias[4];
#pragma unroll
  for (int t = 0; t < 4; ++t) {
    const int j = t * 16 + col;
    bias[t] = (j < 32) ? bmu[j] : blv[j - 32];
  }

  const int ntiles = (n + 15) >> 4;
  for (int tile = blockIdx.x * 4 + wv; tile < ntiles; tile += gridDim.x * 4) {
    const int row0 = tile << 4;
    for (int r = 0; r < 16; ++r) {
      const int i = row0 + r;
      int start = 0, end = 0;
      if (i < n) { start = row_ptr[i]; end = row_ptr[i + 1]; }
      float a0 = 0, a1 = 0, a2 = 0, a3 = 0, a4 = 0, a5 = 0, a6 = 0, a7 = 0;
      int idx = (start + g < end) ? pairs[start + g] : n;
      for (int base = start; base < end; base += 8) {
        int idxn = (base + 8 + g < end) ? pairs[base + 8 + g] : n;
        const float4 rr = *(const float4*)(hsin + (size_t)idx * 64 + q * 8);
        const __half2* hp = (const __half2*)&rr;
        float2 f0 = __half22float2(hp[0]), f1 = __half22float2(hp[1]);
        float2 f2 = __half22float2(hp[2]), f3 = __half22float2(hp[3]);
        a0 += f0.x; a1 += f0.y; a2 += f1.x; a3 += f1.y;
        a4 += f2.x; a5 += f2.y; a6 += f3.x; a7 += f3.y;
        idx = idxn;
      }
      const int iself = (i < n) ? i : n;
      const float4 sr = *(const float4*)(hsin + (size_t)iself * 64 + q * 8);
      if (g == 0 && i < n) {
        const __half2* hp = (const __half2*)&sr;
        float2 f0 = __half22float2(hp[0]), f1 = __half22float2(hp[1]);
        float2 f2 = __half22float2(hp[2]), f3 = __half22float2(hp[3]);
        a0 += f0.x; a1 += f0.y; a2 += f1.x; a3 += f1.y;
        a4 += f2.x; a5 += f2.y; a6 += f3.x; a7 += f3.y;
      }
      a0 += __shfl_xor(a0, 32); a1 += __shfl_xor(a1, 32);
      a2 += __shfl_xor(a2, 32); a3 += __shfl_xor(a3, 32);
      a4 += __shfl_xor(a4, 32); a5 += __shfl_xor(a5, 32);
      a6 += __shfl_xor(a6, 32); a7 += __shfl_xor(a7, 32);
      a0 += __shfl_xor(a0, 16); a1 += __shfl_xor(a1, 16);
      a2 += __shfl_xor(a2, 16); a3 += __shfl_xor(a3, 16);
      a4 += __shfl_xor(a4, 16); a5 += __shfl_xor(a5, 16);
      a6 += __shfl_xor(a6, 16); a7 += __shfl_xor(a7, 16);
      const float di = rsqrtf((float)(1 + end - start));
      if (g < 2) {
        half8 yv;
        yv[0] = (_Float16)(di * a0); yv[1] = (_Float16)(di * a1);
        yv[2] = (_Float16)(di * a2); yv[3] = (_Float16)(di * a3);
        yv[4] = (_Float16)(di * a4); yv[5] = (_Float16)(di * a5);
        yv[6] = (_Float16)(di * a6); yv[7] = (_Float16)(di * a7);
        *(half8*)(ylds + r * YSTRIDE + g * 64 + q * 8) = yv;
      }
    }
    float4v acc[4];
#pragma unroll
    for (int t = 0; t < 4; ++t) acc[t] = (float4v){bias[t], bias[t], bias[t], bias[t]};
#pragma unroll
    for (int s2 = 0; s2 < 4; ++s2) {
      half8 af = *(half8*)(ylds + col * YSTRIDE + s2 * 32 + quad * 8);
      const int sW = s2 & 1;
#pragma unroll
      for (int t = 0; t < 4; ++t)
        acc[t] = __builtin_amdgcn_mfma_f32_16x16x32_f16(af, bfrag[sW][t], acc[t], 0, 0, 0);
    }
#pragma unroll
    for (int t = 0; t < 4; ++t)
#pragma unroll
      for (int reg = 0; reg < 4; ++reg) {
        const int row = row0 + quad * 4 + reg;
        if (row < n) {
          const int j = t * 16 + col;
          if (j < 32)
            out_mu[(size_t)row * 32 + j] = acc[t][reg];
          else
            out_lv[(size_t)row * 32 + (j - 32)] = acc[t][reg];
        }
      }
  }
}

extern "C" void kernel_launch(void* const* d_in, const int* in_sizes, int n_in,
                              void* d_out, int out_size, void* d_ws, size_t ws_size,
                              hipStream_t stream) {
  const float* x = (const float*)d_in[0];
  const int* ei = (const int*)d_in[1];  // [2, E] row-major int32
  const float* W1 = (const float*)d_in[2];
  const float* b1 = (const float*)d_in[3];
  const float* Wmu = (const float*)d_in[4];
  const float* bmu = (const float*)d_in[5];
  const float* Wlv = (const float*)d_in[6];
  const float* blv = (const float*)d_in[7];

  const int N = in_sizes[0] / 64;
  const int E = in_sizes[1] / 2;
  const int* src = ei;
  const int* dst = ei + E;

  const int NBK = (N + BKT_NODES - 1) >> BKT_SHIFT;  // 196 buckets (<=256)
  const int NBLK = (E + CHUNK - 1) / CHUNK;          // 196 A-blocks
  const int FL = NBK * NBLK;

  auto align256 = [](size_t v) { return (v + 255) & ~(size_t)255; };
  char* p = (char*)d_ws;
  int* row_ptr = (int*)p;  p += align256((size_t)(N + 1) * 4);
  float* dinv = (float*)p; p += align256((size_t)N * 4);
  int* bsum = (int*)p;     p += align256((size_t)1024 * 4);
  int* cnt = (int*)p;      p += align256((size_t)FL * 4);  // -> offsets after scan
  int* pairs = (int*)p;    p += align256((size_t)E * 4);
  __half* xs = (__half*)p; p += align256((size_t)(N + 1) * 64 * 2);
  size_t tmp_bytes = (size_t)E * 8;
  size_t hs_bytes = (size_t)(N + 1) * 64 * 2;
  int2* tmp = (int2*)p;    // union: tmp dead after bucket_build; hs written later
  __half* hs = (__half*)p; p += align256(tmp_bytes > hs_bytes ? tmp_bytes : hs_bytes);

  float* out_mu = (float*)d_out;
  float* out_lv = out_mu + (size_t)N * 32;

  const int NB_F = (FL + 1023) / 1024;
  const int n4 = N * 16;

  // --- CSR build (no global atomics) ---
  bucket_count<<<NBLK, 256, 0, stream>>>(dst, cnt, E, NBK, NBLK);
  block_sums<<<NB_F, 1024, 0, stream>>>(cnt, bsum, FL);
  scan_bsums<<<1, 1024, 0, stream>>>(bsum, NB_F);
  scan_apply<<<NB_F, 1024, 0, stream>>>(cnt, bsum, FL);
  bucket_scatter<<<NBLK, 256, 0, stream>>>(src, dst, cnt, tmp, E, NBK, NBLK);
  bucket_build<<<NBK, 512, 0, stream>>>(tmp, cnt, row_ptr, dinv, pairs, N, NBK, NBLK, E);

  // --- tables (after bucket_build: hs aliases tmp) ---
  cast_scale<<<(n4 + 32 + 255) / 256, 256, 0, stream>>>(x, dinv, xs, hs, n4, N);

  // --- aggregation + fused dense layers (MFMA epilogue) ---
  const int ntiles = (N + 15) / 16;
  const int ablocks = (ntiles + 3) / 4;  // 1 tile (16 rows) per wave
  agg_layer1<<<ablocks, 256, 0, stream>>>(xs, pairs, row_ptr, W1, b1, hs, N);
  agg_layer2<<<ablocks, 256, 0, stream>>>(hs, pairs, row_ptr, Wmu, bmu, Wlv, blv,
                                          out_mu, out_lv, N);
}

// Round 8
// 253.417 us; speedup vs baseline: 1.2305x; 1.2305x over previous
//
#include <hip/hip_runtime.h>
#include <hip/hip_fp16.h>

// GCN VGAE encoder:
//   h  = relu((A @ x) @ W1 + b1)          [associativity: A(xW) == (Ax)W]
//   mu = (A @ h) @ Wmu + bmu ; lv = (A @ h) @ Wlv + blv
// A = D^-1/2 (Adj + I) D^-1/2, deg on dst side. dinv folded into tables:
//   xs[s]=dinv_s*x[s]; hs[i]=dinv_i*relu(...); y_i = dinv_i*(sum_e xs[src]+xs[i])
//
// R8 (vs R7): R7's occupancy push regressed (more waves -> same 2.4TB/s
// request rate); R2's fp32 kernel proved the memory path can do 50 Glines/s
// vs R7's 38 -> waves are MLP-starved, not too few. Revert to R6 config
// (K'=256, bounds(256,4), 1 fold) and interleave 4 rows per wave in the
// gather phase (4 independent pairs->gather chains in flight). Accumulate in
// packed half2 (v_pk_add_f16): no per-iteration unpack (fp16 accum of ~17
// terms adds ~2e-3 err, threshold 1e-2).

#define BKT_SHIFT 9
#define BKT_NODES 512
#define CHUNK 8192

typedef __attribute__((ext_vector_type(8))) _Float16 half8;
typedef __attribute__((ext_vector_type(4))) float float4v;
typedef __attribute__((ext_vector_type(4))) unsigned uint4v;

__device__ __forceinline__ int imin(int a, int b) { return a < b ? a : b; }
__device__ __forceinline__ int imax(int a, int b) { return a > b ? a : b; }
__device__ __forceinline__ unsigned h2u(__half2 v) {
  union { __half2 h; unsigned u; } c; c.h = v; return c.u;
}
__device__ __forceinline__ __half2 u2h(unsigned x) {
  union { unsigned u; __half2 h; } c; c.u = x; return c.h;
}

// ---------------- scan building blocks (for the (bucket,block) table) ------

__global__ __launch_bounds__(1024) void block_sums(const int* __restrict__ in,
                                                   int* __restrict__ bsum, int n) {
  __shared__ int s[1024];
  int t = threadIdx.x;
  int i = blockIdx.x * 1024 + t;
  s[t] = (i < n) ? in[i] : 0;
  __syncthreads();
  for (int off = 512; off > 0; off >>= 1) {
    if (t < off) s[t] += s[t + off];
    __syncthreads();
  }
  if (t == 0) bsum[blockIdx.x] = s[0];
}

__global__ __launch_bounds__(1024) void scan_bsums(int* __restrict__ bsum, int nb) {
  __shared__ int s[1024];
  int t = threadIdx.x;
  int v = (t < nb) ? bsum[t] : 0;
  s[t] = v;
  __syncthreads();
  for (int off = 1; off < 1024; off <<= 1) {
    int u = (t >= off) ? s[t - off] : 0;
    __syncthreads();
    s[t] += u;
    __syncthreads();
  }
  if (t < nb) bsum[t] = s[t] - v;  // exclusive
}

__global__ __launch_bounds__(1024) void scan_apply(int* __restrict__ data,
                                                   const int* __restrict__ bofs, int n) {
  __shared__ int s[1024];
  int t = threadIdx.x;
  int i = blockIdx.x * 1024 + t;
  int c = (i < n) ? data[i] : 0;
  s[t] = c;
  __syncthreads();
  for (int off = 1; off < 1024; off <<= 1) {
    int u = (t >= off) ? s[t - off] : 0;
    __syncthreads();
    s[t] += u;
    __syncthreads();
  }
  if (i < n) data[i] = bofs[blockIdx.x] + s[t] - c;
}

// ---------------- two-level CSR build (no global atomics) ------------------

// A0: per-chunk bucket histogram -> cnt[bucket*nblk + block] (bucket-major).
__global__ __launch_bounds__(256) void bucket_count(const int* __restrict__ dst,
                                                    int* __restrict__ cnt,
                                                    int E, int nbk, int nblk) {
  __shared__ int hist[256];
  int t = threadIdx.x;
  hist[t] = 0;
  __syncthreads();
  int base = blockIdx.x * CHUNK;
  int end = imin(base + CHUNK, E);
  for (int e = base + t; e < end; e += 256) atomicAdd(&hist[dst[e] >> BKT_SHIFT], 1);
  __syncthreads();
  if (t < nbk) cnt[t * nblk + blockIdx.x] = hist[t];
}

// A1: re-read edges; LDS cursors from scanned bases; contiguous runs to tmp.
__global__ __launch_bounds__(256) void bucket_scatter(const int* __restrict__ src,
                                                      const int* __restrict__ dst,
                                                      const int* __restrict__ ofs,
                                                      int2* __restrict__ tmp,
                                                      int E, int nbk, int nblk) {
  __shared__ int cur[256];
  int t = threadIdx.x;
  if (t < nbk) cur[t] = ofs[t * nblk + blockIdx.x];
  __syncthreads();
  int base = blockIdx.x * CHUNK;
  int end = imin(base + CHUNK, E);
  for (int e = base + t; e < end; e += 256) {
    int d = dst[e];
    int pos = atomicAdd(&cur[d >> BKT_SHIFT], 1);
    tmp[pos] = make_int2(src[e], d);
  }
}

// B: one block per bucket. LDS node histogram -> LDS scan -> row_ptr/dinv
// (coalesced) -> LDS-cursor fill of pairs inside the bucket's window.
__global__ __launch_bounds__(512) void bucket_build(const int2* __restrict__ tmp,
                                                    const int* __restrict__ ofs,
                                                    int* __restrict__ row_ptr,
                                                    float* __restrict__ dinv,
                                                    int* __restrict__ pairs,
                                                    int n, int nbk, int nblk, int E) {
  __shared__ int hist[BKT_NODES];
  __shared__ int scn[BKT_NODES];
  const int b = blockIdx.x;
  const int t = threadIdx.x;
  const int node0 = b << BKT_SHIFT;
  hist[t] = 0;
  __syncthreads();
  const int s = ofs[b * nblk];
  const int e = (b + 1 < nbk) ? ofs[(b + 1) * nblk] : E;
  for (int k = s + t; k < e; k += 512) atomicAdd(&hist[tmp[k].y - node0], 1);
  __syncthreads();
  int v = hist[t];
  scn[t] = v;
  __syncthreads();
  for (int off = 1; off < 512; off <<= 1) {
    int u = (t >= off) ? scn[t - off] : 0;
    __syncthreads();
    scn[t] += u;
    __syncthreads();
  }
  int excl = s + scn[t] - v;  // exclusive prefix = CSR start of node0+t
  int node = node0 + t;
  if (node < n) {
    row_ptr[node] = excl;
    dinv[node] = rsqrtf(1.0f + (float)v);  // deg includes self-loop
  }
  if (b == nbk - 1 && t == 0) row_ptr[n] = E;
  hist[t] = excl;  // reuse as cursor
  __syncthreads();
  for (int k = s + t; k < e; k += 512) {
    int2 p = tmp[k];
    int pos = atomicAdd(&hist[p.y - node0], 1);
    pairs[pos] = p.x;
  }
}

// ---------------- table prep ----------------

// xs[i] = dinv[i] * x[i] in fp16; zeros sentinel row `nrow` of xs and hs.
__global__ __launch_bounds__(256) void cast_scale(const float* __restrict__ x,
                                                  const float* __restrict__ dinv,
                                                  __half* __restrict__ xs,
                                                  __half* __restrict__ hs,
                                                  int n4, int nrow) {
  int i = blockIdx.x * blockDim.x + threadIdx.x;
  if (i < n4) {
    float4 v = ((const float4*)x)[i];
    float d = dinv[i >> 4];
    __half2* o = (__half2*)(xs + (size_t)i * 4);
    o[0] = __floats2half2_rn(d * v.x, d * v.y);
    o[1] = __floats2half2_rn(d * v.z, d * v.w);
  } else if (i < n4 + 32) {
    int j = i - n4;
    if (j < 16)
      ((float2*)(xs + (size_t)nrow * 64))[j] = make_float2(0.f, 0.f);
    else
      ((float2*)(hs + (size_t)nrow * 64))[j - 16] = make_float2(0.f, 0.f);
  }
}

// ---------------- aggregation + fused dense via MFMA ----------------
// Wave handles 16 rows (4 groups of 4 rows interleaved). Per row: 8 edge
// slots (lane=8g+q, 16B of 8 halves/lane), packed-half2 accumulate; 4 rows'
// pairs-prefetch + gather chains run concurrently (4x MLP). One xor-32 fold
// (slots 8->4), self-term on g==0, di-scale, store to wave-private LDS
// A-tile ylds[row][(g&3)*64 + 8q+c] (K'=256; last 4-slot reduction rides the
// MFMA K-dim, B = W replicated over the 4 slots). 8 k-steps x 4 n-tiles of
// mfma_f32_16x16x32_f16, bias in C-init.
// A layout: A[m=lane&15][k=(lane>>4)*8+j]; C/D: col=lane&15, row=quad*4+reg.

#define YSTRIDE 264  // 256 + 8 halves pad

__global__ __launch_bounds__(256, 4) void agg_layer1(const __half* __restrict__ xs,
                                                     const int* __restrict__ pairs,
                                                     const int* __restrict__ row_ptr,
                                                     const float* __restrict__ W1,
                                                     const float* __restrict__ b1,
                                                     __half* __restrict__ hs, int n) {
  __shared__ _Float16 ylds_all[4][16 * YSTRIDE];
  __shared__ float dilds_all[4][16];
  const int wv = threadIdx.x >> 6;
  _Float16* ylds = ylds_all[wv];
  float* dilds = dilds_all[wv];
  const int lane = threadIdx.x & 63;
  const int g = lane >> 3, q = lane & 7;
  const int quad = lane >> 4, col = lane & 15;

  // B-fragments: k = s2*32 + quad*8 + jj; feature = k & 63 -> sW = s2 & 1.
  half8 bfrag[2][4];
#pragma unroll
  for (int s = 0; s < 2; ++s)
#pragma unroll
    for (int t = 0; t < 4; ++t)
#pragma unroll
      for (int jj = 0; jj < 8; ++jj)
        bfrag[s][t][jj] = (_Float16)W1[(s * 32 + quad * 8 + jj) * 64 + t * 16 + col];
  float bias[4];
#pragma unroll
  for (int t = 0; t < 4; ++t) bias[t] = b1[t * 16 + col];

  const int ntiles = (n + 15) >> 4;
  for (int tile = blockIdx.x * 4 + wv; tile < ntiles; tile += gridDim.x * 4) {
    const int row0 = tile << 4;
#pragma unroll 1
    for (int rg = 0; rg < 4; ++rg) {  // 4 rows interleaved per group
      int start[4], end[4], idx[4];
      __half2 acc[4][4];
      int maxdeg = 0;
#pragma unroll
      for (int j = 0; j < 4; ++j) {
        const int i = row0 + rg * 4 + j;
        start[j] = 0; end[j] = 0;
        if (i < n) { start[j] = row_ptr[i]; end[j] = row_ptr[i + 1]; }
        maxdeg = imax(maxdeg, end[j] - start[j]);
#pragma unroll
        for (int k = 0; k < 4; ++k) acc[j][k] = u2h(0u);
        idx[j] = (start[j] + g < end[j]) ? pairs[start[j] + g] : n;
      }
      const int iters = (maxdeg + 7) >> 3;
#pragma unroll 1
      for (int it = 0; it < iters; ++it) {
        int nidx[4];
#pragma unroll
        for (int j = 0; j < 4; ++j) {
          const int ofs = start[j] + (it + 1) * 8 + g;
          nidx[j] = (ofs < end[j]) ? pairs[ofs] : n;
        }
#pragma unroll
        for (int j = 0; j < 4; ++j) {
          const float4 rr = *(const float4*)(xs + (size_t)idx[j] * 64 + q * 8);
          const __half2* hp = (const __half2*)&rr;
#pragma unroll
          for (int k = 0; k < 4; ++k) acc[j][k] = __hadd2(acc[j][k], hp[k]);
        }
#pragma unroll
        for (int j = 0; j < 4; ++j) idx[j] = nidx[j];
      }
#pragma unroll
      for (int j = 0; j < 4; ++j) {
        const int i = row0 + rg * 4 + j;
        // self term (once, on g==0 lanes)
        if (g == 0 && i < n) {
          const float4 sr = *(const float4*)(xs + (size_t)i * 64 + q * 8);
          const __half2* hp = (const __half2*)&sr;
#pragma unroll
          for (int k = 0; k < 4; ++k) acc[j][k] = __hadd2(acc[j][k], hp[k]);
        }
        // fold slots g and g^4 (lane xor 32)
#pragma unroll
        for (int k = 0; k < 4; ++k) {
          unsigned u = __shfl_xor(h2u(acc[j][k]), 32);
          acc[j][k] = __hadd2(acc[j][k], u2h(u));
        }
        const float di = rsqrtf((float)(1 + end[j] - start[j]));
        const __half hdi = __float2half(di);
        const __half2 di2 = __halves2half2(hdi, hdi);
        uint4v st;
        st.x = h2u(__hmul2(di2, acc[j][0]));
        st.y = h2u(__hmul2(di2, acc[j][1]));
        st.z = h2u(__hmul2(di2, acc[j][2]));
        st.w = h2u(__hmul2(di2, acc[j][3]));
        *(uint4v*)(ylds + (rg * 4 + j) * YSTRIDE + (g & 3) * 64 + q * 8) = st;
        if (lane == 0) dilds[rg * 4 + j] = di;
      }
    }
    // MFMA: D = A(16x256) * B'(256x64) + bias
    float4v acc[4];
#pragma unroll
    for (int t = 0; t < 4; ++t) acc[t] = (float4v){bias[t], bias[t], bias[t], bias[t]};
#pragma unroll
    for (int s2 = 0; s2 < 8; ++s2) {
      half8 af = *(half8*)(ylds + col * YSTRIDE + s2 * 32 + quad * 8);
      const int sW = s2 & 1;
#pragma unroll
      for (int t = 0; t < 4; ++t)
        acc[t] = __builtin_amdgcn_mfma_f32_16x16x32_f16(af, bfrag[sW][t], acc[t], 0, 0, 0);
    }
    const float4 dis = *(const float4*)(dilds + quad * 4);
    const float dd[4] = {dis.x, dis.y, dis.z, dis.w};
#pragma unroll
    for (int t = 0; t < 4; ++t)
#pragma unroll
      for (int reg = 0; reg < 4; ++reg) {
        const int row = row0 + quad * 4 + reg;
        if (row < n)
          hs[(size_t)row * 64 + t * 16 + col] =
              __float2half(dd[reg] * fmaxf(acc[t][reg], 0.f));
      }
  }
}

// Layer 2: same structure; B' = [Wmu | Wlv] (64 cols), fp32 outputs.
__global__ __launch_bounds__(256, 4) void agg_layer2(const __half* __restrict__ hsin,
                                                     const int* __restrict__ pairs,
                                                     const int* __restrict__ row_ptr,
                                                     const float* __restrict__ Wmu,
                                                     const float* __restrict__ bmu,
                                                     const float* __restrict__ Wlv,
                                                     const float* __restrict__ blv,
                                                     float* __restrict__ out_mu,
                                                     float* __restrict__ out_lv, int n) {
  __shared__ _Float16 ylds_all[4][16 * YSTRIDE];
  const int wv = threadIdx.x >> 6;
  _Float16* ylds = ylds_all[wv];
  const int lane = threadIdx.x & 63;
  const int g = lane >> 3, q = lane & 7;
  const int quad = lane >> 4, col = lane & 15;

  half8 bfrag[2][4];
#pragma unroll
  for (int s = 0; s < 2; ++s)
#pragma unroll
    for (int t = 0; t < 4; ++t) {
      const int j = t * 16 + col;
      const float* W = (j < 32) ? Wmu : Wlv;
      const int jc = j & 31;
#pragma unroll
      for (int jj = 0; jj < 8; ++jj)
        bfrag[s][t][jj] = (_Float16)W[(s * 32 + quad * 8 + jj) * 32 + jc];
    }
  float bias[4];
#pragma unroll
  for (int t = 0; t < 4; ++t) {
    const int j = t * 16 + col;
    bias[t] = (j < 32) ? bmu[j] : blv[j - 32];
  }

  const int ntiles = (n + 15) >> 4;
  for (int tile = blockIdx.x * 4 + wv; tile < ntiles; tile += gridDim.x * 4) {
    const int row0 = tile << 4;
#pragma unroll 1
    for (int rg = 0; rg < 4; ++rg) {
      int start[4], end[4], idx[4];
      __half2 acc[4][4];
      int maxdeg = 0;
#pragma unroll
      for (int j = 0; j < 4; ++j) {
        const int i = row0 + rg * 4 + j;
        start[j] = 0; end[j] = 0;
        if (i < n) { start[j] = row_ptr[i]; end[j] = row_ptr[i + 1]; }
        maxdeg = imax(maxdeg, end[j] - start[j]);
#pragma unroll
        for (int k = 0; k < 4; ++k) acc[j][k] = u2h(0u);
        idx[j] = (start[j] + g < end[j]) ? pairs[start[j] + g] : n;
      }
      const int iters = (maxdeg + 7) >> 3;
#pragma unroll 1
      for (int it = 0; it < iters; ++it) {
        int nidx[4];
#pragma unroll
        for (int j = 0; j < 4; ++j) {
          const int ofs = start[j] + (it + 1) * 8 + g;
          nidx[j] = (ofs < end[j]) ? pairs[ofs] : n;
        }
#pragma unroll
        for (int j = 0; j < 4; ++j) {
          const float4 rr = *(const float4*)(hsin + (size_t)idx[j] * 64 + q * 8);
          const __half2* hp = (const __half2*)&rr;
#pragma unroll
          for (int k = 0; k < 4; ++k) acc[j][k] = __hadd2(acc[j][k], hp[k]);
        }
#pragma unroll
        for (int j = 0; j < 4; ++j) idx[j] = nidx[j];
      }
#pragma unroll
      for (int j = 0; j < 4; ++j) {
        const int i = row0 + rg * 4 + j;
        if (g == 0 && i < n) {
          const float4 sr = *(const float4*)(hsin + (size_t)i * 64 + q * 8);
          const __half2* hp = (const __half2*)&sr;
#pragma unroll
          for (int k = 0; k < 4; ++k) acc[j][k] = __hadd2(acc[j][k], hp[k]);
        }
#pragma unroll
        for (int k = 0; k < 4; ++k) {
          unsigned u = __shfl_xor(h2u(acc[j][k]), 32);
          acc[j][k] = __hadd2(acc[j][k], u2h(u));
        }
        const float di = rsqrtf((float)(1 + end[j] - start[j]));
        const __half hdi = __float2half(di);
        const __half2 di2 = __halves2half2(hdi, hdi);
        uint4v st;
        st.x = h2u(__hmul2(di2, acc[j][0]));
        st.y = h2u(__hmul2(di2, acc[j][1]));
        st.z = h2u(__hmul2(di2, acc[j][2]));
        st.w = h2u(__hmul2(di2, acc[j][3]));
        *(uint4v*)(ylds + (rg * 4 + j) * YSTRIDE + (g & 3) * 64 + q * 8) = st;
      }
    }
    float4v acc[4];
#pragma unroll
    for (int t = 0; t < 4; ++t) acc[t] = (float4v){bias[t], bias[t], bias[t], bias[t]};
#pragma unroll
    for (int s2 = 0; s2 < 8; ++s2) {
      half8 af = *(half8*)(ylds + col * YSTRIDE + s2 * 32 + quad * 8);
      const int sW = s2 & 1;
#pragma unroll
      for (int t = 0; t < 4; ++t)
        acc[t] = __builtin_amdgcn_mfma_f32_16x16x32_f16(af, bfrag[sW][t], acc[t], 0, 0, 0);
    }
#pragma unroll
    for (int t = 0; t < 4; ++t)
#pragma unroll
      for (int reg = 0; reg < 4; ++reg) {
        const int row = row0 + quad * 4 + reg;
        if (row < n) {
          const int j = t * 16 + col;
          if (j < 32)
            out_mu[(size_t)row * 32 + j] = acc[t][reg];
          else
            out_lv[(size_t)row * 32 + (j - 32)] = acc[t][reg];
        }
      }
  }
}

extern "C" void kernel_launch(void* const* d_in, const int* in_sizes, int n_in,
                              void* d_out, int out_size, void* d_ws, size_t ws_size,
                              hipStream_t stream) {
  const float* x = (const float*)d_in[0];
  const int* ei = (const int*)d_in[1];  // [2, E] row-major int32
  const float* W1 = (const float*)d_in[2];
  const float* b1 = (const float*)d_in[3];
  const float* Wmu = (const float*)d_in[4];
  const float* bmu = (const float*)d_in[5];
  const float* Wlv = (const float*)d_in[6];
  const float* blv = (const float*)d_in[7];

  const int N = in_sizes[0] / 64;
  const int E = in_sizes[1] / 2;
  const int* src = ei;
  const int* dst = ei + E;

  const int NBK = (N + BKT_NODES - 1) >> BKT_SHIFT;  // 196 buckets (<=256)
  const int NBLK = (E + CHUNK - 1) / CHUNK;          // 196 A-blocks
  const int FL = NBK * NBLK;

  auto align256 = [](size_t v) { return (v + 255) & ~(size_t)255; };
  char* p = (char*)d_ws;
  int* row_ptr = (int*)p;  p += align256((size_t)(N + 1) * 4);
  float* dinv = (float*)p; p += align256((size_t)N * 4);
  int* bsum = (int*)p;     p += align256((size_t)1024 * 4);
  int* cnt = (int*)p;      p += align256((size_t)FL * 4);  // -> offsets after scan
  int* pairs = (int*)p;    p += align256((size_t)E * 4);
  __half* xs = (__half*)p; p += align256((size_t)(N + 1) * 64 * 2);
  size_t tmp_bytes = (size_t)E * 8;
  size_t hs_bytes = (size_t)(N + 1) * 64 * 2;
  int2* tmp = (int2*)p;    // union: tmp dead after bucket_build; hs written later
  __half* hs = (__half*)p; p += align256(tmp_bytes > hs_bytes ? tmp_bytes : hs_bytes);

  float* out_mu = (float*)d_out;
  float* out_lv = out_mu + (size_t)N * 32;

  const int NB_F = (FL + 1023) / 1024;
  const int n4 = N * 16;

  // --- CSR build (no global atomics) ---
  bucket_count<<<NBLK, 256, 0, stream>>>(dst, cnt, E, NBK, NBLK);
  block_sums<<<NB_F, 1024, 0, stream>>>(cnt, bsum, FL);
  scan_bsums<<<1, 1024, 0, stream>>>(bsum, NB_F);
  scan_apply<<<NB_F, 1024, 0, stream>>>(cnt, bsum, FL);
  bucket_scatter<<<NBLK, 256, 0, stream>>>(src, dst, cnt, tmp, E, NBK, NBLK);
  bucket_build<<<NBK, 512, 0, stream>>>(tmp, cnt, row_ptr, dinv, pairs, N, NBK, NBLK, E);

  // --- tables (after bucket_build: hs aliases tmp) ---
  cast_scale<<<(n4 + 32 + 255) / 256, 256, 0, stream>>>(x, dinv, xs, hs, n4, N);

  // --- aggregation + fused dense layers (MFMA epilogue) ---
  const int ntiles = (N + 15) / 16;
  const int ablocks = (ntiles + 3) / 4;  // 1 tile (16 rows) per wave
  agg_layer1<<<ablocks, 256, 0, stream>>>(xs, pairs, row_ptr, W1, b1, hs, N);
  agg_layer2<<<ablocks, 256, 0, stream>>>(hs, pairs, row_ptr, Wmu, bmu, Wlv, blv,
                                          out_mu, out_lv, N);
}